// Round 5
// baseline (117.142 us; speedup 1.0000x reference)
//
#include <hip/hip_runtime.h>
#include <math.h>

// Problem constants
#define B_     16
#define C_     32
#define D_     2
#define HW_    4096               // 64*64
#define NPIX   (B_ * D_ * HW_)    // 131072 pixels
#define NPAIRP 576                // padded pair slots: row c has rlen(c)=4*(c/4+1)
#define NROWSP 592                // + zero rows (margin)

// ---------------------------------------------------------------------------
// Prep (validated R2/R3): fold weight [O,C,C] into padded symmetric pair table
//   wpad[kp][o]. Row c starts at kpbase(c)=4*(c+2a(a-1)+ab), a=c>>2, b=c&3.
//   Slot j<=c: W[o,c,j]+W[o,j,c] (diag once); pad slots = 0.
// ---------------------------------------------------------------------------
__global__ void prep_wsym(const float* __restrict__ w, float* __restrict__ wpad) {
    int idx = blockIdx.x * blockDim.x + threadIdx.x;
    const int total1 = 32 * 32 * 32;
    const int totalz = (NROWSP - NPAIRP) * 32;
    if (idx < total1) {
        int o = idx & 31;
        int j = (idx >> 5) & 31;
        int c = idx >> 10;
        int a = c >> 2, b = c & 3;
        int rlen = (a + 1) << 2;
        if (j >= rlen) return;
        int kb = 4 * (c + 2 * a * (a - 1) + a * b);
        float v = 0.0f;
        if (j <= c) {
            const float* wo = w + o * (C_ * C_);
            v = (j == c) ? wo[c * C_ + c] : (wo[c * C_ + j] + wo[j * C_ + c]);
        }
        wpad[(kb + j) * 32 + o] = v;
    } else if (idx < total1 + totalz) {
        wpad[NPAIRP * 32 + (idx - total1)] = 0.0f;
    }
}

// ---------------------------------------------------------------------------
// Main kernel. Block = 256 threads = 4 waves over the SAME 128 pixels:
//   wave (wv, pg):  wv = o-half (16 outputs), pg = pixel group (64 pixels).
// Each lane owns ONE pixel -> 32 acc VGPRs. 4 waves/SIMD residency (16/CU)
// hides the lgkm latency that capped R3 at 66% VALUBusy.
//
// Trig staged TRANSPOSED in LDS: trig[c][cos|sin][128] -> all reads
// lane-stride-1 (2 lanes/bank, conflict-free; R3 measured 0 conflicts).
// Weights wave-uniform -> s_load_dwordx16 stream (scalar pipe, K$-cached).
// ---------------------------------------------------------------------------
#define TPB 256

__global__ __launch_bounds__(TPB, 4) void bilinear_kernel(
    const float* __restrict__ x,
    const float* __restrict__ wpad,
    const float* __restrict__ bias,
    float* __restrict__ out)
{
    __shared__ float trig[C_][2][128];   // 32 KB -> 5 blocks/CU (grid caps at 4)

    const int l    = threadIdx.x & 63;
    const int wv   = __builtin_amdgcn_readfirstlane((threadIdx.x >> 6) & 1);
    const int pg   = __builtin_amdgcn_readfirstlane(threadIdx.x >> 7);
    const int pix  = (pg << 6) + l;              // my pixel within block
    const int P0   = blockIdx.x * 128;
    const int b    = P0 >> 13;
    const int d    = (P0 >> 12) & 1;
    const int hw0  = P0 & 4095;                  // 128-aligned, block stays in (b,d)
    const int pixbase = b * (C_ * D_ * HW_) + d * HW_ + hw0;  // + pix + c*8192

    // ---- prologue: 256 threads stage 128 pixels x 32 channels ----
    {
        const int sp  = threadIdx.x & 127;       // staging pixel
        const int chh = threadIdx.x >> 7;        // channel half
        #pragma unroll 4
        for (int cc = 0; cc < 16; ++cc) {
            int c = chh * 16 + cc;
            float xv = x[pixbase + sp + c * (D_ * HW_)];
            float s, co;
            __sincosf(xv, &s, &co);
            trig[c][0][sp] = co;
            trig[c][1][sp] = s;
        }
    }
    __syncthreads();

    float accr[16], acci[16];
    #pragma unroll
    for (int q = 0; q < 16; ++q) { accr[q] = 0.f; acci[q] = 0.f; }

    const float* __restrict__ wbase = wpad + wv * 16;   // our o-half of each row

    #pragma unroll 1
    for (int eb = 0; eb < 8; ++eb) {
        const int e0 = eb << 2;
        float ce[4], se[4];
        #pragma unroll
        for (int j = 0; j < 4; ++j) {
            ce[j] = trig[e0 + j][0][pix];
            se[j] = trig[e0 + j][1][pix];
        }
        int kpb = 8 * eb * (eb + 1);   // kpbase(4*eb)
        #pragma unroll 1
        for (int c = e0; c < C_; ++c) {
            const float cv = trig[c][0][pix];
            const float sv = trig[c][1][pix];
            const float* __restrict__ wr = wbase + (kpb + e0) * 32;  // uniform -> s_load
            #pragma unroll
            for (int p = 0; p < 4; ++p) {
                float ur = fmaf(cv, ce[p], -(sv * se[p]));
                float ui = fmaf(cv, se[p],   sv * ce[p]);
                #pragma unroll
                for (int q = 0; q < 16; ++q) {
                    const float wq = wr[p * 32 + q];
                    accr[q] = fmaf(wq, ur, accr[q]);
                    acci[q] = fmaf(wq, ui, acci[q]);
                }
            }
            kpb += ((c >> 2) + 1) << 2;   // += rowlen(c)
        }
    }

    // ---- epilogue: angle + bias, coalesced stores ----
    #pragma unroll
    for (int q = 0; q < 16; ++q) {
        const int o = wv * 16 + q;
        out[pixbase + pix + o * (D_ * HW_)] = atan2f(acci[q], accr[q]) + bias[o];
    }
}

// ---------------------------------------------------------------------------
extern "C" void kernel_launch(void* const* d_in, const int* in_sizes, int n_in,
                              void* d_out, int out_size, void* d_ws, size_t ws_size,
                              hipStream_t stream) {
    const float* x    = (const float*)d_in[0];
    const float* w    = (const float*)d_in[1];
    const float* bias = (const float*)d_in[2];
    float* out        = (float*)d_out;
    float* wpad       = (float*)d_ws;   // needs NROWSP*32*4 = 75,776 B

    {
        int n = 32 * 32 * 32 + (NROWSP - NPAIRP) * 32;
        int tpb = 256;
        prep_wsym<<<(n + tpb - 1) / tpb, tpb, 0, stream>>>(w, wpad);
    }
    {
        int grid = NPIX / 128;   // 1024 blocks, 4 waves each
        bilinear_kernel<<<grid, TPB, 0, stream>>>(x, wpad, bias, out);
    }
}